// Round 11
// baseline (40.275 us; speedup 1.0000x reference)
//
#include <hip/hip_runtime.h>

#define EXP2F(x)  __builtin_amdgcn_exp2f(x)    // v_exp_f32 = 2^x
#define LOG2FD(x) __builtin_amdgcn_logf(x)     // v_log_f32 = log2(x)
#define L2E 1.4426950408889634f
#define T1F 1.2621774e-29f                     // 2^-96: min trustworthy MFMA sum

typedef __attribute__((ext_vector_type(8))) short bf16x8;  // 8 bf16 = 4 VGPR
typedef __attribute__((ext_vector_type(4))) float f32x4;
typedef __attribute__((ext_vector_type(2))) unsigned int u32x2;

#define MFMA16(A, B, C) __builtin_amdgcn_mfma_f32_16x16x32_bf16((A), (B), (C), 0, 0, 0)

union U8 { unsigned int u[4]; bf16x8 v; };

// split 8 f32 into bf16-truncated hi + bf16-truncated residual lo, packed for MFMA
__device__ __forceinline__ void split_pack(const float* w, bf16x8& hi, bf16x8& lo) {
  U8 a, b;
#pragma unroll
  for (int k = 0; k < 4; ++k) {
    float x0 = w[2*k], x1 = w[2*k+1];
    unsigned u0 = __float_as_uint(x0) & 0xFFFF0000u;
    unsigned u1 = __float_as_uint(x1) & 0xFFFF0000u;
    float r0 = x0 - __uint_as_float(u0);
    float r1 = x1 - __uint_as_float(u1);
    a.u[k] = (u0 >> 16) | u1;
    b.u[k] = ((__float_as_uint(r0) & 0xFFFF0000u) >> 16) |
             (__float_as_uint(r1) & 0xFFFF0000u);
  }
  hi = a.v; lo = b.v;
}

// xor-32 max via permlane32_swap (VALU pipe, no LDS)
__device__ __forceinline__ float pmax32(float v) {
  u32x2 r = __builtin_amdgcn_permlane32_swap(__float_as_uint(v), __float_as_uint(v),
                                             false, false);
  return fmaxf(__uint_as_float(r.x), __uint_as_float(r.y));
}

// build K fragments from pos (L1-resident 256B table), no persistent c2 registers
__device__ __forceinline__ void buildK(const float2* pos2, float inv,
                                       int b15, int g,
                                       bf16x8& KA1, bf16x8& KA2, bf16x8& KB1, bf16x8& KB2) {
  float2 p0 = pos2[b15];
  float2 p1 = pos2[b15 + 16];
  float ka[8], kb[8];
#pragma unroll
  for (int e = 0; e < 8; ++e) {
    float2 pj = pos2[8*g + e];
    float dx0 = p0.x - pj.x, dy0 = p0.y - pj.y;
    float dx1 = p1.x - pj.x, dy1 = p1.y - pj.y;
    ka[e] = EXP2F((-0.5f*L2E) * inv * (dx0*dx0 + dy0*dy0));
    kb[e] = EXP2F((-0.5f*L2E) * inv * (dx1*dx1 + dy1*dy1));
  }
  split_pack(ka, KA1, KA2);
  split_pack(kb, KB1, KB2);
}

// rare exact per-row logsumexp: arg_j = H_j - c2(i,j)*inv, H from LDS row
__device__ __noinline__ float exact_lse(const float2* pos2, const float* HB,
                                        int i, float inv) {
  float2 pi = pos2[i];
  float m = -3.4e38f;
#pragma unroll 1
  for (int j = 0; j < 32; ++j) {
    float2 pj = pos2[j];
    float dx = pi.x - pj.x, dy = pi.y - pj.y;
    float arg = fmaf((0.5f*L2E)*(dx*dx + dy*dy), -inv, HB[j]);
    m = fmaxf(m, arg);
  }
  float s = 0.f;
#pragma unroll 1
  for (int j = 0; j < 32; ++j) {
    float2 pj = pos2[j];
    float dx = pi.x - pj.x, dy = pi.y - pj.y;
    float arg = fmaf((0.5f*L2E)*(dx*dx + dy*dy), -inv, HB[j]);
    s += EXP2F(arg - m);
  }
  return m + LOG2FD(s);
}

// Two packed-tile MFMA softmins (8 batches x 2 chains per tile), interleaved.
// H1/H2 in B-layout (col = lane&15, k = 8g+e); modified in place to d = H - hm.
// Results (nde*raw) stored D-layout to Ts slot 0 / slot 1.
template<bool CHECKED>
__device__ __forceinline__ void ksoft2(float* Ts, float* Hdump,
    float* H1, float* H2,
    bf16x8 KA1, bf16x8 KA2, bf16x8 KB1, bf16x8 KB2,
    float nde, float inv, int b15, int g, const float2* pos2) {
  float* Hq[2] = {H1, H2};
  float hm[2];
  bf16x8 w1[2], w2[2];
#pragma unroll
  for (int q = 0; q < 2; ++q) {
    float* H = Hq[q];
    float m = fmaxf(fmaxf(fmaxf(H[0], H[1]), fmaxf(H[2], H[3])),
                    fmaxf(fmaxf(H[4], H[5]), fmaxf(H[6], H[7])));
    m = fmaxf(m, __shfl_xor(m, 16));
    m = pmax32(m);
    hm[q] = m;
    float w[8];
#pragma unroll
    for (int e = 0; e < 8; ++e) { H[e] -= m; w[e] = EXP2F(H[e]); }
    split_pack(w, w1[q], w2[q]);
  }
  const f32x4 z = {0.f, 0.f, 0.f, 0.f};
  f32x4 a0[2], a1[2];
#pragma unroll
  for (int q = 0; q < 2; ++q) { a0[q] = MFMA16(KA1, w1[q], z);     a1[q] = MFMA16(KB1, w1[q], z); }
#pragma unroll
  for (int q = 0; q < 2; ++q) { a0[q] = MFMA16(KA2, w1[q], a0[q]); a1[q] = MFMA16(KB2, w1[q], a1[q]); }
#pragma unroll
  for (int q = 0; q < 2; ++q) { a0[q] = MFMA16(KA1, w2[q], a0[q]); a1[q] = MFMA16(KB1, w2[q], a1[q]); }
#pragma unroll
  for (int q = 0; q < 2; ++q) {
    float* H = Hq[q];   // holds d = H - hm
    float r0[4], r1[4];
#pragma unroll
    for (int r = 0; r < 4; ++r) {
      r0[r] = hm[q] + LOG2FD(a0[q][r]);
      r1[r] = hm[q] + LOG2FD(a1[q][r]);
    }
    if (CHECKED) {
      float mn = fminf(fminf(fminf(a0[q][0], a0[q][1]), fminf(a0[q][2], a0[q][3])),
                       fminf(fminf(a1[q][0], a1[q][1]), fminf(a1[q][2], a1[q][3])));
      if (__any(mn < T1F)) {        // rescue scale (+96)
        float wb[8];
#pragma unroll
        for (int e = 0; e < 8; ++e) wb[e] = EXP2F(H[e] + 96.f);
        bf16x8 u1, u2;
        split_pack(wb, u1, u2);
        f32x4 b0 = MFMA16(KA1, u1, z);
        b0 = MFMA16(KA2, u1, b0);
        b0 = MFMA16(KA1, u2, b0);
        f32x4 b1 = MFMA16(KB1, u1, z);
        b1 = MFMA16(KB2, u1, b1);
        b1 = MFMA16(KB1, u2, b1);
        bool mybad = false;
#pragma unroll
        for (int r = 0; r < 4; ++r) {
          if (a0[q][r] < T1F) r0[r] = (hm[q] - 96.f) + LOG2FD(b0[r]);
          if (a1[q][r] < T1F) r1[r] = (hm[q] - 96.f) + LOG2FD(b1[r]);
          mybad |= (a0[q][r] < T1F) && (b0[r] < T1F);
          mybad |= (a1[q][r] < T1F) && (b1[r] < T1F);
        }
        if (__any(mybad)) {         // beyond 192 log2-units: exact fixup (very rare)
          float4 h0 = {H[0]+hm[q], H[1]+hm[q], H[2]+hm[q], H[3]+hm[q]};
          float4 h1 = {H[4]+hm[q], H[5]+hm[q], H[6]+hm[q], H[7]+hm[q]};
          *(float4*)&Hdump[b15*36 + 8*g]     = h0;
          *(float4*)&Hdump[b15*36 + 8*g + 4] = h1;
          asm volatile("" ::: "memory");
          const float* HB = &Hdump[b15*36];
#pragma unroll
          for (int r = 0; r < 4; ++r) {
            if ((a0[q][r] < T1F) && (b0[r] < T1F)) r0[r] = exact_lse(pos2, HB, 4*g + r, inv);
            if ((a1[q][r] < T1F) && (b1[r] < T1F)) r1[r] = exact_lse(pos2, HB, 16 + 4*g + r, inv);
          }
        }
      }
    }
    float4 v0 = {nde*r0[0], nde*r0[1], nde*r0[2], nde*r0[3]};
    float4 v1 = {nde*r1[0], nde*r1[1], nde*r1[2], nde*r1[3]};
    float* Tq = Ts + q * 576;
    *(float4*)&Tq[b15*36 + 4*g]      = v0;   // D-layout: col b15, rows 4g+r
    *(float4*)&Tq[b15*36 + 4*g + 16] = v1;   // rows 16+4g+r
  }
}

// One wave per block, 8 batches per wave, 2 packed tiles:
//   tile1 cols 0-7: F_ba(batch), cols 8-15: G_ab(batch)   (cross pair)
//   tile2 cols 0-7: F_aa(batch), cols 8-15: G_bb(batch)   (self chains)
__global__ __launch_bounds__(64, 4) void sink_kernel(
    const float* __restrict__ pred, const float* __restrict__ tgt,
    const float* __restrict__ pos, float* __restrict__ ws) {
  __shared__ __align__(16) float sT[2][576];     // transpose slots (tile1, tile2)
  __shared__ __align__(16) float sHb[16 * 36];   // rescue H dump

  const int lid  = threadIdx.x;        // 0..63, one wave
  const int b15  = lid & 15;           // tile column
  const int g    = lid >> 4;
  const int h8   = (b15 >> 3) & 1;     // 0: F-side cols, 1: G-side cols
  const int bcol = b15 & 7;            // batch within the wave's group
  const int bbase = blockIdx.x * 8;
  const float2* pos2 = (const float2*)pos;
  float* Tw = &sT[0][0];
  float* Hd = &sHb[0];

  // masses in B-layout rows 8g+e for this lane's batch; pre-select per column role
  float m1[8], m2[8];
  {
    const float* pr = &pred[(bbase + bcol) * 32 + 8 * g];
    const float* tr = &tgt [(bbase + bcol) * 32 + 8 * g];
    float4 p0 = *(const float4*)&pr[0];
    float4 p1 = *(const float4*)&pr[4];
    float4 t0 = *(const float4*)&tr[0];
    float4 t1 = *(const float4*)&tr[4];
    float la[8], lb[8];
    la[0]=LOG2FD(p0.x); la[1]=LOG2FD(p0.y); la[2]=LOG2FD(p0.z); la[3]=LOG2FD(p0.w);
    la[4]=LOG2FD(p1.x); la[5]=LOG2FD(p1.y); la[6]=LOG2FD(p1.z); la[7]=LOG2FD(p1.w);
    lb[0]=LOG2FD(t0.x); lb[1]=LOG2FD(t0.y); lb[2]=LOG2FD(t0.z); lb[3]=LOG2FD(t0.w);
    lb[4]=LOG2FD(t1.x); lb[5]=LOG2FD(t1.y); lb[6]=LOG2FD(t1.z); lb[7]=LOG2FD(t1.w);
#pragma unroll
    for (int e = 0; e < 8; ++e) {
      m1[e] = h8 ? la[e] : lb[e];   // tile1 H-mass (ft: bl2 | gt: al2)
      m2[e] = h8 ? lb[e] : la[e];   // tile2 H-mass (fa: al2 | gb: bl2); also loss mass
    }
  }

  bf16x8 KA1, KA2, KB1, KB2;
  float Xo[8], Xc[8], W[8];   // tile1 own pot, tile1 cross pot, tile2 self pot
  float H1[8], H2[8];

  // ---- init at eps0 = 8: H = mass (potential term zero) ----
  buildK(pos2, 0.125f, b15, g, KA1, KA2, KB1, KB2);
#pragma unroll
  for (int e = 0; e < 8; ++e) { H1[e] = m1[e]; H2[e] = m2[e]; }
  ksoft2<false>(Tw, Hd, H1, H2, KA1, KA2, KB1, KB2, -8.f/9.f, 0.125f, b15, g, pos2);
  {
    const int own = b15 * 36 + 8 * g, crs = (b15 ^ 8) * 36 + 8 * g;
    float4 o0 = *(const float4*)&Tw[own];
    float4 o1 = *(const float4*)&Tw[own + 4];
    float4 c0 = *(const float4*)&Tw[crs];
    float4 c1 = *(const float4*)&Tw[crs + 4];
    float4 s0 = *(const float4*)&Tw[576 + own];
    float4 s1 = *(const float4*)&Tw[576 + own + 4];
    Xo[0]=o0.x; Xo[1]=o0.y; Xo[2]=o0.z; Xo[3]=o0.w;
    Xo[4]=o1.x; Xo[5]=o1.y; Xo[6]=o1.z; Xo[7]=o1.w;
    Xc[0]=c0.x; Xc[1]=c0.y; Xc[2]=c0.z; Xc[3]=c0.w;
    Xc[4]=c1.x; Xc[5]=c1.y; Xc[6]=c1.z; Xc[7]=c1.w;
    W[0]=s0.x;  W[1]=s0.y;  W[2]=s0.z;  W[3]=s0.w;
    W[4]=s1.x;  W[5]=s1.y;  W[6]=s1.z;  W[7]=s1.w;
  }

  // eps schedule [8, 8, 2, 0.5, 0.125 | 0.03125, 0.01, 0.01-extrap]
  const float INV[8] = {0.125f, 0.125f, 0.5f, 2.f, 8.f, 32.f, 100.f, 100.f};
  const float NDE[8] = {-8.f/9.f, -8.f/9.f, -2.f/3.f, -1.f/3.f, -1.f/9.f,
                        -1.f/33.f, -1.f/101.f, -1.f/101.f};
  float curInv = 0.125f;

  // ---- phase A: k = 0..4 (unchecked, averaged) ----
#pragma unroll 1
  for (int k = 0; k < 5; ++k) {
    const float inv = INV[k], nde = NDE[k];
    if (inv != curInv) { buildK(pos2, inv, b15, g, KA1, KA2, KB1, KB2); curInv = inv; }
#pragma unroll
    for (int e = 0; e < 8; ++e) {
      H1[e] = fmaf(Xc[e], inv, m1[e]);
      H2[e] = fmaf(W[e],  inv, m2[e]);
    }
    ksoft2<false>(Tw, Hd, H1, H2, KA1, KA2, KB1, KB2, nde, inv, b15, g, pos2);
    const int own = b15 * 36 + 8 * g, crs = (b15 ^ 8) * 36 + 8 * g;
    float4 o0 = *(const float4*)&Tw[own];
    float4 o1 = *(const float4*)&Tw[own + 4];
    float4 c0 = *(const float4*)&Tw[crs];
    float4 c1 = *(const float4*)&Tw[crs + 4];
    float4 s0 = *(const float4*)&Tw[576 + own];
    float4 s1 = *(const float4*)&Tw[576 + own + 4];
    Xo[0]=0.5f*(Xo[0]+o0.x); Xo[1]=0.5f*(Xo[1]+o0.y); Xo[2]=0.5f*(Xo[2]+o0.z); Xo[3]=0.5f*(Xo[3]+o0.w);
    Xo[4]=0.5f*(Xo[4]+o1.x); Xo[5]=0.5f*(Xo[5]+o1.y); Xo[6]=0.5f*(Xo[6]+o1.z); Xo[7]=0.5f*(Xo[7]+o1.w);
    Xc[0]=0.5f*(Xc[0]+c0.x); Xc[1]=0.5f*(Xc[1]+c0.y); Xc[2]=0.5f*(Xc[2]+c0.z); Xc[3]=0.5f*(Xc[3]+c0.w);
    Xc[4]=0.5f*(Xc[4]+c1.x); Xc[5]=0.5f*(Xc[5]+c1.y); Xc[6]=0.5f*(Xc[6]+c1.z); Xc[7]=0.5f*(Xc[7]+c1.w);
    W[0]=0.5f*(W[0]+s0.x);  W[1]=0.5f*(W[1]+s0.y);  W[2]=0.5f*(W[2]+s0.z);  W[3]=0.5f*(W[3]+s0.w);
    W[4]=0.5f*(W[4]+s1.x);  W[5]=0.5f*(W[5]+s1.y);  W[6]=0.5f*(W[6]+s1.z);  W[7]=0.5f*(W[7]+s1.w);
  }

  // ---- phase B: k = 5..7 (checked; k=7 extrapolation assigns) ----
#pragma unroll 1
  for (int k = 5; k < 8; ++k) {
    const float inv = INV[k], nde = NDE[k];
    if (inv != curInv) { buildK(pos2, inv, b15, g, KA1, KA2, KB1, KB2); curInv = inv; }
#pragma unroll
    for (int e = 0; e < 8; ++e) {
      H1[e] = fmaf(Xc[e], inv, m1[e]);
      H2[e] = fmaf(W[e],  inv, m2[e]);
    }
    ksoft2<true>(Tw, Hd, H1, H2, KA1, KA2, KB1, KB2, nde, inv, b15, g, pos2);
    const int own = b15 * 36 + 8 * g, crs = (b15 ^ 8) * 36 + 8 * g;
    float4 o0 = *(const float4*)&Tw[own];
    float4 o1 = *(const float4*)&Tw[own + 4];
    float4 c0 = *(const float4*)&Tw[crs];
    float4 c1 = *(const float4*)&Tw[crs + 4];
    float4 s0 = *(const float4*)&Tw[576 + own];
    float4 s1 = *(const float4*)&Tw[576 + own + 4];
    if (k < 7) {
      Xo[0]=0.5f*(Xo[0]+o0.x); Xo[1]=0.5f*(Xo[1]+o0.y); Xo[2]=0.5f*(Xo[2]+o0.z); Xo[3]=0.5f*(Xo[3]+o0.w);
      Xo[4]=0.5f*(Xo[4]+o1.x); Xo[5]=0.5f*(Xo[5]+o1.y); Xo[6]=0.5f*(Xo[6]+o1.z); Xo[7]=0.5f*(Xo[7]+o1.w);
      Xc[0]=0.5f*(Xc[0]+c0.x); Xc[1]=0.5f*(Xc[1]+c0.y); Xc[2]=0.5f*(Xc[2]+c0.z); Xc[3]=0.5f*(Xc[3]+c0.w);
      Xc[4]=0.5f*(Xc[4]+c1.x); Xc[5]=0.5f*(Xc[5]+c1.y); Xc[6]=0.5f*(Xc[6]+c1.z); Xc[7]=0.5f*(Xc[7]+c1.w);
      W[0]=0.5f*(W[0]+s0.x);  W[1]=0.5f*(W[1]+s0.y);  W[2]=0.5f*(W[2]+s0.z);  W[3]=0.5f*(W[3]+s0.w);
      W[4]=0.5f*(W[4]+s1.x);  W[5]=0.5f*(W[5]+s1.y);  W[6]=0.5f*(W[6]+s1.z);  W[7]=0.5f*(W[7]+s1.w);
    } else {
      Xo[0]=o0.x; Xo[1]=o0.y; Xo[2]=o0.z; Xo[3]=o0.w;
      Xo[4]=o1.x; Xo[5]=o1.y; Xo[6]=o1.z; Xo[7]=o1.w;
      W[0]=s0.x;  W[1]=s0.y;  W[2]=s0.z;  W[3]=s0.w;
      W[4]=s1.x;  W[5]=s1.y;  W[6]=s1.z;  W[7]=s1.w;
    }
  }

  // ---- loss: lane covers rows 8g..8g+7 of its (batch, side) column ----
  // h8=0: p*(e^-Faa - e^-Fba); h8=1: t*(e^-Gbb - e^-Gab). massL = m2.
  float part = 0.f;
#pragma unroll
  for (int e = 0; e < 8; ++e)
    part += EXP2F(m2[e]) * (EXP2F(-W[e]) - EXP2F(-Xo[e]));

  part += __shfl_xor(part, 1);
  part += __shfl_xor(part, 2);
  part += __shfl_xor(part, 4);
  part += __shfl_xor(part, 8);
  part += __shfl_xor(part, 16);
  part += __shfl_xor(part, 32);
  if (lid == 0) ws[blockIdx.x] = part;
}

__global__ __launch_bounds__(256) void reduce_kernel(
    const float* __restrict__ ws, float* __restrict__ out, int n, float scale) {
  float s = 0.f;
  for (int i = threadIdx.x; i < n; i += 256) s += ws[i];
  s += __shfl_xor(s, 32);
  s += __shfl_xor(s, 16);
  s += __shfl_xor(s, 8);
  s += __shfl_xor(s, 4);
  s += __shfl_xor(s, 2);
  s += __shfl_xor(s, 1);
  __shared__ float a[4];
  if ((threadIdx.x & 63) == 0) a[threadIdx.x >> 6] = s;
  __syncthreads();
  if (threadIdx.x == 0) out[0] = ((a[0] + a[1]) + (a[2] + a[3])) * scale;
}

extern "C" void kernel_launch(void* const* d_in, const int* in_sizes, int n_in,
                              void* d_out, int out_size, void* d_ws, size_t ws_size,
                              hipStream_t stream) {
  const float* pred = (const float*)d_in[0];
  const float* tgt  = (const float*)d_in[1];
  const float* pos  = (const float*)d_in[2];
  const int B = in_sizes[0] / 32;        // 32768 batches
  const int nblocks = B / 8;             // 8 batches per 1-wave block = 4096
  float* ws = (float*)d_ws;

  sink_kernel<<<nblocks, 64, 0, stream>>>(pred, tgt, pos, ws);
  reduce_kernel<<<1, 256, 0, stream>>>(ws, (float*)d_out, nblocks,
                                       1.005f / (float)B);
}

// Round 12
// 35.782 us; speedup vs baseline: 1.1256x; 1.1256x over previous
//
#include <hip/hip_runtime.h>

#define EXP2F(x)  __builtin_amdgcn_exp2f(x)    // v_exp_f32 = 2^x
#define LOG2FD(x) __builtin_amdgcn_logf(x)     // v_log_f32 = log2(x)
#define L2E 1.4426950408889634f
#define T1F 1.2621774e-29f                     // 2^-96: min trustworthy MFMA sum

typedef __attribute__((ext_vector_type(8))) short bf16x8;  // 8 bf16 = 4 VGPR
typedef __attribute__((ext_vector_type(4))) float f32x4;
typedef __attribute__((ext_vector_type(2))) unsigned int u32x2;

#define MFMA16(A, B, C) __builtin_amdgcn_mfma_f32_16x16x32_bf16((A), (B), (C), 0, 0, 0)
// ds_swizzle xor within 32-lane group
#define SWZX(v, M) __int_as_float(__builtin_amdgcn_ds_swizzle(__float_as_int(v), ((M) << 10) | 0x1F))

union U8 { unsigned int u[4]; bf16x8 v; };

// split 8 f32 into bf16-truncated hi + bf16-truncated residual lo, packed for MFMA
__device__ __forceinline__ void split_pack(const float* w, bf16x8& hi, bf16x8& lo) {
  U8 a, b;
#pragma unroll
  for (int k = 0; k < 4; ++k) {
    float x0 = w[2*k], x1 = w[2*k+1];
    unsigned u0 = __float_as_uint(x0) & 0xFFFF0000u;
    unsigned u1 = __float_as_uint(x1) & 0xFFFF0000u;
    float r0 = x0 - __uint_as_float(u0);
    float r1 = x1 - __uint_as_float(u1);
    a.u[k] = (u0 >> 16) | u1;
    b.u[k] = ((__float_as_uint(r0) & 0xFFFF0000u) >> 16) |
             (__float_as_uint(r1) & 0xFFFF0000u);
  }
  hi = a.v; lo = b.v;
}

// xor-32 max via permlane32_swap (VALU pipe, no LDS)
__device__ __forceinline__ float pmax32(float v) {
  u32x2 r = __builtin_amdgcn_permlane32_swap(__float_as_uint(v), __float_as_uint(v),
                                             false, false);
  return fmaxf(__uint_as_float(r.x), __uint_as_float(r.y));
}

// build K fragments from pos (L1-resident 256B table), no persistent c2 registers
__device__ __forceinline__ void buildK(const float2* pos2, float inv,
                                       int b15, int g,
                                       bf16x8& KA1, bf16x8& KA2, bf16x8& KB1, bf16x8& KB2) {
  float2 p0 = pos2[b15];
  float2 p1 = pos2[b15 + 16];
  float ka[8], kb[8];
#pragma unroll
  for (int e = 0; e < 8; ++e) {
    float2 pj = pos2[8*g + e];
    float dx0 = p0.x - pj.x, dy0 = p0.y - pj.y;
    float dx1 = p1.x - pj.x, dy1 = p1.y - pj.y;
    ka[e] = EXP2F((-0.5f*L2E) * inv * (dx0*dx0 + dy0*dy0));
    kb[e] = EXP2F((-0.5f*L2E) * inv * (dx1*dx1 + dy1*dy1));
  }
  split_pack(ka, KA1, KA2);
  split_pack(kb, KB1, KB2);
}

// rare exact per-row logsumexp: arg_j = H_j - c2(i,j)*inv, H from LDS row
__device__ __noinline__ float exact_lse(const float2* pos2, const float* HB,
                                        int i, float inv) {
  float2 pi = pos2[i];
  float m = -3.4e38f;
#pragma unroll 1
  for (int j = 0; j < 32; ++j) {
    float2 pj = pos2[j];
    float dx = pi.x - pj.x, dy = pi.y - pj.y;
    float arg = fmaf((0.5f*L2E)*(dx*dx + dy*dy), -inv, HB[j]);
    m = fmaxf(m, arg);
  }
  float s = 0.f;
#pragma unroll 1
  for (int j = 0; j < 32; ++j) {
    float2 pj = pos2[j];
    float dx = pi.x - pj.x, dy = pi.y - pj.y;
    float arg = fmaf((0.5f*L2E)*(dx*dx + dy*dy), -inv, HB[j]);
    s += EXP2F(arg - m);
  }
  return m + LOG2FD(s);
}

// Two packed-tile MFMA softmins (8 batches x 2 chains per tile), interleaved.
// H1/H2 in B-layout (col = lane&15, k = 8g+e); modified in place to d = H - hm.
// Results (nde*raw) stored D-layout to Ts slot 0 / slot 1.
template<bool CHECKED>
__device__ __forceinline__ void ksoft2(float* Ts, float* Hdump,
    float* H1, float* H2,
    bf16x8 KA1, bf16x8 KA2, bf16x8 KB1, bf16x8 KB2,
    float nde, float inv, int b15, int g, const float2* pos2) {
  float* Hq[2] = {H1, H2};
  float hm[2];
  bf16x8 w1[2], w2[2];
#pragma unroll
  for (int q = 0; q < 2; ++q) {
    float* H = Hq[q];
    float m = fmaxf(fmaxf(fmaxf(H[0], H[1]), fmaxf(H[2], H[3])),
                    fmaxf(fmaxf(H[4], H[5]), fmaxf(H[6], H[7])));
    m = fmaxf(m, __shfl_xor(m, 16));
    m = pmax32(m);
    hm[q] = m;
    float w[8];
#pragma unroll
    for (int e = 0; e < 8; ++e) { H[e] -= m; w[e] = EXP2F(H[e]); }
    split_pack(w, w1[q], w2[q]);
  }
  const f32x4 z = {0.f, 0.f, 0.f, 0.f};
  f32x4 a0[2], a1[2];
#pragma unroll
  for (int q = 0; q < 2; ++q) { a0[q] = MFMA16(KA1, w1[q], z);     a1[q] = MFMA16(KB1, w1[q], z); }
#pragma unroll
  for (int q = 0; q < 2; ++q) { a0[q] = MFMA16(KA2, w1[q], a0[q]); a1[q] = MFMA16(KB2, w1[q], a1[q]); }
#pragma unroll
  for (int q = 0; q < 2; ++q) { a0[q] = MFMA16(KA1, w2[q], a0[q]); a1[q] = MFMA16(KB1, w2[q], a1[q]); }
#pragma unroll
  for (int q = 0; q < 2; ++q) {
    float* H = Hq[q];   // holds d = H - hm
    float r0[4], r1[4];
#pragma unroll
    for (int r = 0; r < 4; ++r) {
      r0[r] = hm[q] + LOG2FD(a0[q][r]);
      r1[r] = hm[q] + LOG2FD(a1[q][r]);
    }
    if (CHECKED) {
      float mn = fminf(fminf(fminf(a0[q][0], a0[q][1]), fminf(a0[q][2], a0[q][3])),
                       fminf(fminf(a1[q][0], a1[q][1]), fminf(a1[q][2], a1[q][3])));
      if (__any(mn < T1F)) {        // rescue scale (+96)
        float wb[8];
#pragma unroll
        for (int e = 0; e < 8; ++e) wb[e] = EXP2F(H[e] + 96.f);
        bf16x8 u1, u2;
        split_pack(wb, u1, u2);
        f32x4 b0 = MFMA16(KA1, u1, z);
        b0 = MFMA16(KA2, u1, b0);
        b0 = MFMA16(KA1, u2, b0);
        f32x4 b1 = MFMA16(KB1, u1, z);
        b1 = MFMA16(KB2, u1, b1);
        b1 = MFMA16(KB1, u2, b1);
        bool mybad = false;
#pragma unroll
        for (int r = 0; r < 4; ++r) {
          if (a0[q][r] < T1F) r0[r] = (hm[q] - 96.f) + LOG2FD(b0[r]);
          if (a1[q][r] < T1F) r1[r] = (hm[q] - 96.f) + LOG2FD(b1[r]);
          mybad |= (a0[q][r] < T1F) && (b0[r] < T1F);
          mybad |= (a1[q][r] < T1F) && (b1[r] < T1F);
        }
        if (__any(mybad)) {         // beyond 192 log2-units: exact fixup (very rare)
          float4 h0 = {H[0]+hm[q], H[1]+hm[q], H[2]+hm[q], H[3]+hm[q]};
          float4 h1 = {H[4]+hm[q], H[5]+hm[q], H[6]+hm[q], H[7]+hm[q]};
          *(float4*)&Hdump[b15*36 + 8*g]     = h0;
          *(float4*)&Hdump[b15*36 + 8*g + 4] = h1;
          asm volatile("" ::: "memory");
          const float* HB = &Hdump[b15*36];
#pragma unroll
          for (int r = 0; r < 4; ++r) {
            if ((a0[q][r] < T1F) && (b0[r] < T1F)) r0[r] = exact_lse(pos2, HB, 4*g + r, inv);
            if ((a1[q][r] < T1F) && (b1[r] < T1F)) r1[r] = exact_lse(pos2, HB, 16 + 4*g + r, inv);
          }
        }
      }
    }
    float4 v0 = {nde*r0[0], nde*r0[1], nde*r0[2], nde*r0[3]};
    float4 v1 = {nde*r1[0], nde*r1[1], nde*r1[2], nde*r1[3]};
    float* Tq = Ts + q * 576;
    *(float4*)&Tq[b15*36 + 4*g]      = v0;   // D-layout: col b15, rows 4g+r
    *(float4*)&Tq[b15*36 + 4*g + 16] = v1;   // rows 16+4g+r
  }
}

// One wave per block, 8 batches per wave, 2 packed tiles:
//   tile1 cols 0-7: F_ba(batch), cols 8-15: G_ab(batch)   (cross pair)
//   tile2 cols 0-7: F_aa(batch), cols 8-15: G_bb(batch)   (self chains)
// Mirror-column potential (Xc) obtained via ds_swizzle xor8 of Xo (no registers).
__global__ __launch_bounds__(64, 4) void sink_kernel(
    const float* __restrict__ pred, const float* __restrict__ tgt,
    const float* __restrict__ pos, float* __restrict__ ws) {
  __shared__ __align__(16) float sT[2][576];     // transpose slots (tile1, tile2)
  __shared__ __align__(16) float sHb[16 * 36];   // rescue H dump

  const int lid  = threadIdx.x;        // 0..63, one wave
  const int b15  = lid & 15;           // tile column
  const int g    = lid >> 4;
  const int h8   = (b15 >> 3) & 1;     // 0: F-side cols, 1: G-side cols
  const int bcol = b15 & 7;            // batch within the wave's group
  const int bbase = blockIdx.x * 8;
  const float2* pos2 = (const float2*)pos;
  float* Tw = &sT[0][0];
  float* Hd = &sHb[0];

  // masses in B-layout rows 8g+e for this lane's batch; pre-select per column role
  float m1[8], m2[8];
  {
    const float* pr = &pred[(bbase + bcol) * 32 + 8 * g];
    const float* tr = &tgt [(bbase + bcol) * 32 + 8 * g];
    float4 p0 = *(const float4*)&pr[0];
    float4 p1 = *(const float4*)&pr[4];
    float4 t0 = *(const float4*)&tr[0];
    float4 t1 = *(const float4*)&tr[4];
    float la[8], lb[8];
    la[0]=LOG2FD(p0.x); la[1]=LOG2FD(p0.y); la[2]=LOG2FD(p0.z); la[3]=LOG2FD(p0.w);
    la[4]=LOG2FD(p1.x); la[5]=LOG2FD(p1.y); la[6]=LOG2FD(p1.z); la[7]=LOG2FD(p1.w);
    lb[0]=LOG2FD(t0.x); lb[1]=LOG2FD(t0.y); lb[2]=LOG2FD(t0.z); lb[3]=LOG2FD(t0.w);
    lb[4]=LOG2FD(t1.x); lb[5]=LOG2FD(t1.y); lb[6]=LOG2FD(t1.z); lb[7]=LOG2FD(t1.w);
#pragma unroll
    for (int e = 0; e < 8; ++e) {
      m1[e] = h8 ? la[e] : lb[e];   // tile1 H-mass (ft: bl2 | gt: al2)
      m2[e] = h8 ? lb[e] : la[e];   // tile2 H-mass (fa: al2 | gb: bl2); also loss mass
    }
  }

  bf16x8 KA1, KA2, KB1, KB2;
  float Xo[8], W[8];    // tile1 own pot (F_ba | G_ab), tile2 self pot (F_aa | G_bb)

  // ---- init at eps0 = 8: H = mass (potential term zero) ----
  buildK(pos2, 0.125f, b15, g, KA1, KA2, KB1, KB2);
  {
    float H1[8], H2[8];
#pragma unroll
    for (int e = 0; e < 8; ++e) { H1[e] = m1[e]; H2[e] = m2[e]; }
    ksoft2<false>(Tw, Hd, H1, H2, KA1, KA2, KB1, KB2, -8.f/9.f, 0.125f, b15, g, pos2);
  }
  {
    const int own = b15 * 36 + 8 * g;
    float4 o0 = *(const float4*)&Tw[own];
    float4 o1 = *(const float4*)&Tw[own + 4];
    float4 s0 = *(const float4*)&Tw[576 + own];
    float4 s1 = *(const float4*)&Tw[576 + own + 4];
    Xo[0]=o0.x; Xo[1]=o0.y; Xo[2]=o0.z; Xo[3]=o0.w;
    Xo[4]=o1.x; Xo[5]=o1.y; Xo[6]=o1.z; Xo[7]=o1.w;
    W[0]=s0.x;  W[1]=s0.y;  W[2]=s0.z;  W[3]=s0.w;
    W[4]=s1.x;  W[5]=s1.y;  W[6]=s1.z;  W[7]=s1.w;
  }

  // eps schedule [8, 8, 2, 0.5, 0.125 | 0.03125, 0.01, 0.01-extrap]
  const float INV[8] = {0.125f, 0.125f, 0.5f, 2.f, 8.f, 32.f, 100.f, 100.f};
  const float NDE[8] = {-8.f/9.f, -8.f/9.f, -2.f/3.f, -1.f/3.f, -1.f/9.f,
                        -1.f/33.f, -1.f/101.f, -1.f/101.f};
  float curInv = 0.125f;

  // ---- phase A: k = 0..4 (unchecked, averaged) ----
#pragma unroll 1
  for (int k = 0; k < 5; ++k) {
    const float inv = INV[k], nde = NDE[k];
    if (inv != curInv) { buildK(pos2, inv, b15, g, KA1, KA2, KB1, KB2); curInv = inv; }
    float H1[8], H2[8];
#pragma unroll
    for (int e = 0; e < 8; ++e) {
      float xc = SWZX(Xo[e], 8);            // mirror column's old potential
      H1[e] = fmaf(xc,   inv, m1[e]);
      H2[e] = fmaf(W[e], inv, m2[e]);
    }
    ksoft2<false>(Tw, Hd, H1, H2, KA1, KA2, KB1, KB2, nde, inv, b15, g, pos2);
    const int own = b15 * 36 + 8 * g;
    float4 o0 = *(const float4*)&Tw[own];
    float4 o1 = *(const float4*)&Tw[own + 4];
    float4 s0 = *(const float4*)&Tw[576 + own];
    float4 s1 = *(const float4*)&Tw[576 + own + 4];
    Xo[0]=0.5f*(Xo[0]+o0.x); Xo[1]=0.5f*(Xo[1]+o0.y); Xo[2]=0.5f*(Xo[2]+o0.z); Xo[3]=0.5f*(Xo[3]+o0.w);
    Xo[4]=0.5f*(Xo[4]+o1.x); Xo[5]=0.5f*(Xo[5]+o1.y); Xo[6]=0.5f*(Xo[6]+o1.z); Xo[7]=0.5f*(Xo[7]+o1.w);
    W[0]=0.5f*(W[0]+s0.x);  W[1]=0.5f*(W[1]+s0.y);  W[2]=0.5f*(W[2]+s0.z);  W[3]=0.5f*(W[3]+s0.w);
    W[4]=0.5f*(W[4]+s1.x);  W[5]=0.5f*(W[5]+s1.y);  W[6]=0.5f*(W[6]+s1.z);  W[7]=0.5f*(W[7]+s1.w);
  }

  // ---- phase B: k = 5..7 (checked; k=7 extrapolation assigns) ----
#pragma unroll 1
  for (int k = 5; k < 8; ++k) {
    const float inv = INV[k], nde = NDE[k];
    if (inv != curInv) { buildK(pos2, inv, b15, g, KA1, KA2, KB1, KB2); curInv = inv; }
    float H1[8], H2[8];
#pragma unroll
    for (int e = 0; e < 8; ++e) {
      float xc = SWZX(Xo[e], 8);
      H1[e] = fmaf(xc,   inv, m1[e]);
      H2[e] = fmaf(W[e], inv, m2[e]);
    }
    ksoft2<true>(Tw, Hd, H1, H2, KA1, KA2, KB1, KB2, nde, inv, b15, g, pos2);
    const int own = b15 * 36 + 8 * g;
    float4 o0 = *(const float4*)&Tw[own];
    float4 o1 = *(const float4*)&Tw[own + 4];
    float4 s0 = *(const float4*)&Tw[576 + own];
    float4 s1 = *(const float4*)&Tw[576 + own + 4];
    if (k < 7) {
      Xo[0]=0.5f*(Xo[0]+o0.x); Xo[1]=0.5f*(Xo[1]+o0.y); Xo[2]=0.5f*(Xo[2]+o0.z); Xo[3]=0.5f*(Xo[3]+o0.w);
      Xo[4]=0.5f*(Xo[4]+o1.x); Xo[5]=0.5f*(Xo[5]+o1.y); Xo[6]=0.5f*(Xo[6]+o1.z); Xo[7]=0.5f*(Xo[7]+o1.w);
      W[0]=0.5f*(W[0]+s0.x);  W[1]=0.5f*(W[1]+s0.y);  W[2]=0.5f*(W[2]+s0.z);  W[3]=0.5f*(W[3]+s0.w);
      W[4]=0.5f*(W[4]+s1.x);  W[5]=0.5f*(W[5]+s1.y);  W[6]=0.5f*(W[6]+s1.z);  W[7]=0.5f*(W[7]+s1.w);
    } else {
      Xo[0]=o0.x; Xo[1]=o0.y; Xo[2]=o0.z; Xo[3]=o0.w;
      Xo[4]=o1.x; Xo[5]=o1.y; Xo[6]=o1.z; Xo[7]=o1.w;
      W[0]=s0.x;  W[1]=s0.y;  W[2]=s0.z;  W[3]=s0.w;
      W[4]=s1.x;  W[5]=s1.y;  W[6]=s1.z;  W[7]=s1.w;
    }
  }

  // ---- loss: lane covers rows 8g..8g+7 of its (batch, side) column ----
  // h8=0: p*(e^-Faa - e^-Fba); h8=1: t*(e^-Gbb - e^-Gab). massL = m2.
  float part = 0.f;
#pragma unroll
  for (int e = 0; e < 8; ++e)
    part += EXP2F(m2[e]) * (EXP2F(-W[e]) - EXP2F(-Xo[e]));

  part += __shfl_xor(part, 1);
  part += __shfl_xor(part, 2);
  part += __shfl_xor(part, 4);
  part += __shfl_xor(part, 8);
  part += __shfl_xor(part, 16);
  part += __shfl_xor(part, 32);
  if (lid == 0) ws[blockIdx.x] = part;
}

__global__ __launch_bounds__(256) void reduce_kernel(
    const float* __restrict__ ws, float* __restrict__ out, int n, float scale) {
  float s = 0.f;
  for (int i = threadIdx.x; i < n; i += 256) s += ws[i];
  s += __shfl_xor(s, 32);
  s += __shfl_xor(s, 16);
  s += __shfl_xor(s, 8);
  s += __shfl_xor(s, 4);
  s += __shfl_xor(s, 2);
  s += __shfl_xor(s, 1);
  __shared__ float a[4];
  if ((threadIdx.x & 63) == 0) a[threadIdx.x >> 6] = s;
  __syncthreads();
  if (threadIdx.x == 0) out[0] = ((a[0] + a[1]) + (a[2] + a[3])) * scale;
}

extern "C" void kernel_launch(void* const* d_in, const int* in_sizes, int n_in,
                              void* d_out, int out_size, void* d_ws, size_t ws_size,
                              hipStream_t stream) {
  const float* pred = (const float*)d_in[0];
  const float* tgt  = (const float*)d_in[1];
  const float* pos  = (const float*)d_in[2];
  const int B = in_sizes[0] / 32;        // 32768 batches
  const int nblocks = B / 8;             // 8 batches per 1-wave block = 4096
  float* ws = (float*)d_ws;

  sink_kernel<<<nblocks, 64, 0, stream>>>(pred, tgt, pos, ws);
  reduce_kernel<<<1, 256, 0, stream>>>(ws, (float*)d_out, nblocks,
                                       1.005f / (float)B);
}

// Round 14
// 26.941 us; speedup vs baseline: 1.4949x; 1.3282x over previous
//
#include <hip/hip_runtime.h>
#include <hip/hip_bf16.h>

#define EXP2F(x)  __builtin_amdgcn_exp2f(x)    // v_exp_f32 = 2^x
#define LOG2FD(x) __builtin_amdgcn_logf(x)     // v_log_f32 = log2(x)
#define L2E 1.4426950408889634f
#define T1F 1.2621774e-29f                     // 2^-96: min trustworthy MFMA sum

typedef __attribute__((ext_vector_type(8))) short bf16x8;  // 8 bf16 = 4 VGPR
typedef __attribute__((ext_vector_type(4))) float f32x4;
typedef __attribute__((ext_vector_type(2))) unsigned int u32x2;

#define MFMA16(A, B, C) __builtin_amdgcn_mfma_f32_16x16x32_bf16((A), (B), (C), 0, 0, 0)

union U8 { unsigned int u[4]; bf16x8 v; };
union U8S { unsigned short s[8]; bf16x8 v; };

// split 8 f32 into bf16-truncated hi + bf16-truncated residual lo (K build only;
// K is shared across ALL batches so its rounding error is systematic -> keep split)
__device__ __forceinline__ void split_pack(const float* w, bf16x8& hi, bf16x8& lo) {
  U8 a, b;
#pragma unroll
  for (int k = 0; k < 4; ++k) {
    float x0 = w[2*k], x1 = w[2*k+1];
    unsigned u0 = __float_as_uint(x0) & 0xFFFF0000u;
    unsigned u1 = __float_as_uint(x1) & 0xFFFF0000u;
    float r0 = x0 - __uint_as_float(u0);
    float r1 = x1 - __uint_as_float(u1);
    a.u[k] = (u0 >> 16) | u1;
    b.u[k] = ((__float_as_uint(r0) & 0xFFFF0000u) >> 16) |
             (__float_as_uint(r1) & 0xFFFF0000u);
  }
  hi = a.v; lo = b.v;
}

// single bf16 pack via compiler RNE casts (compiler emits v_cvt_pk_bf16_f32).
// w's rounding error is per-batch random -> cancels in the 32768-batch mean.
__device__ __forceinline__ bf16x8 pack_bf16(const float* w) {
  U8S a;
#pragma unroll
  for (int e = 0; e < 8; ++e) {
    __hip_bfloat16 b = __float2bfloat16(w[e]);
    a.s[e] = reinterpret_cast<const unsigned short&>(b);
  }
  return a.v;
}

// xor-32 max via permlane32_swap (VALU pipe, no LDS)
__device__ __forceinline__ float pmax32(float v) {
  u32x2 r = __builtin_amdgcn_permlane32_swap(__float_as_uint(v), __float_as_uint(v),
                                             false, false);
  return fmaxf(__uint_as_float(r.x), __uint_as_float(r.y));
}

__device__ __forceinline__ void buildK(const float* c2a, const float* c2b, float inv,
                                       bf16x8& KA1, bf16x8& KA2, bf16x8& KB1, bf16x8& KB2) {
  float ka[8], kb[8];
#pragma unroll
  for (int e = 0; e < 8; ++e) { ka[e] = EXP2F(-c2a[e] * inv); kb[e] = EXP2F(-c2b[e] * inv); }
  split_pack(ka, KA1, KA2);
  split_pack(kb, KB1, KB2);
}

__device__ __forceinline__ void pot_assign(float* pot, const float* Ts, int b15, int g) {
  float4 r0 = *(const float4*)&Ts[b15*36 + 8*g];
  float4 r1 = *(const float4*)&Ts[b15*36 + 8*g + 4];
  pot[0]=r0.x; pot[1]=r0.y; pot[2]=r0.z; pot[3]=r0.w;
  pot[4]=r1.x; pot[5]=r1.y; pot[6]=r1.z; pot[7]=r1.w;
}

__device__ __forceinline__ void pot_merge(float* pot, const float* Ts, int b15, int g) {
  float4 r0 = *(const float4*)&Ts[b15*36 + 8*g];
  float4 r1 = *(const float4*)&Ts[b15*36 + 8*g + 4];
  pot[0]=0.5f*(pot[0]+r0.x); pot[1]=0.5f*(pot[1]+r0.y);
  pot[2]=0.5f*(pot[2]+r0.z); pot[3]=0.5f*(pot[3]+r0.w);
  pot[4]=0.5f*(pot[4]+r1.x); pot[5]=0.5f*(pot[5]+r1.y);
  pot[6]=0.5f*(pot[6]+r1.z); pot[7]=0.5f*(pot[7]+r1.w);
}

// rare exact per-row logsumexp: arg_j = H_j - c2(i,j)*inv, H from LDS row
__device__ __noinline__ float exact_lse(const float2* pos2, const float* HB,
                                        int i, float inv) {
  float2 pi = pos2[i];
  float m = -3.4e38f;
#pragma unroll 1
  for (int j = 0; j < 32; ++j) {
    float2 pj = pos2[j];
    float dx = pi.x - pj.x, dy = pi.y - pj.y;
    float arg = fmaf((0.5f*L2E)*(dx*dx + dy*dy), -inv, HB[j]);
    m = fmaxf(m, arg);
  }
  float s = 0.f;
#pragma unroll 1
  for (int j = 0; j < 32; ++j) {
    float2 pj = pos2[j];
    float dx = pi.x - pj.x, dy = pi.y - pj.y;
    float arg = fmaf((0.5f*L2E)*(dx*dx + dy*dy), -inv, HB[j]);
    s += EXP2F(arg - m);
  }
  return m + LOG2FD(s);
}

// NQ interleaved MFMA softmins for 16 batches each (stage-by-stage ILP).
// Hq[q] in B-layout; result nde*raw stored D-layout to slot q of Ts.
// w is single bf16 (RNE); K keeps hi/lo split -> 4 MFMAs per softmin.
template<int NQ, bool CHECKED>
__device__ __forceinline__ void ksoft_multi(float* Ts, float* Hdump,
    const float Hq[][8], bf16x8 KA1, bf16x8 KA2, bf16x8 KB1, bf16x8 KB2,
    float nde, float inv, int b15, int g, const float2* pos2) {
  float hm[NQ], d[NQ][8];
  bf16x8 w1[NQ];
  // stage 1: batch-max + exp + pack (independent per q)
#pragma unroll
  for (int q = 0; q < NQ; ++q) {
    const float* H = Hq[q];
    float m = fmaxf(fmaxf(fmaxf(H[0], H[1]), fmaxf(H[2], H[3])),
                    fmaxf(fmaxf(H[4], H[5]), fmaxf(H[6], H[7])));
    m = fmaxf(m, __shfl_xor(m, 16));
    m = pmax32(m);
    hm[q] = m;
    float w[8];
#pragma unroll
    for (int e = 0; e < 8; ++e) { d[q][e] = H[e] - m; w[e] = EXP2F(d[q][e]); }
    w1[q] = pack_bf16(w);
  }
  // stage 2: 4*NQ MFMAs in 2 rounds of 2*NQ independent ops
  f32x4 a0[NQ], a1[NQ];
  const f32x4 z = {0.f, 0.f, 0.f, 0.f};
#pragma unroll
  for (int q = 0; q < NQ; ++q) { a0[q] = MFMA16(KA1, w1[q], z);     a1[q] = MFMA16(KB1, w1[q], z); }
#pragma unroll
  for (int q = 0; q < NQ; ++q) { a0[q] = MFMA16(KA2, w1[q], a0[q]); a1[q] = MFMA16(KB2, w1[q], a1[q]); }
  // stage 3: logs (+rare rescue), store
#pragma unroll
  for (int q = 0; q < NQ; ++q) {
    float r0[4], r1[4];
#pragma unroll
    for (int r = 0; r < 4; ++r) {
      r0[r] = hm[q] + LOG2FD(a0[q][r]);
      r1[r] = hm[q] + LOG2FD(a1[q][r]);
    }
    if (CHECKED) {
      float mn = fminf(fminf(fminf(a0[q][0], a0[q][1]), fminf(a0[q][2], a0[q][3])),
                       fminf(fminf(a1[q][0], a1[q][1]), fminf(a1[q][2], a1[q][3])));
      if (__any(mn < T1F)) {        // rescue scale (+96)
        float wb[8];
#pragma unroll
        for (int e = 0; e < 8; ++e) wb[e] = EXP2F(d[q][e] + 96.f);
        bf16x8 u1 = pack_bf16(wb);
        f32x4 b0 = MFMA16(KA1, u1, z);
        b0 = MFMA16(KA2, u1, b0);
        f32x4 b1 = MFMA16(KB1, u1, z);
        b1 = MFMA16(KB2, u1, b1);
        bool mybad = false;
#pragma unroll
        for (int r = 0; r < 4; ++r) {
          if (a0[q][r] < T1F) r0[r] = (hm[q] - 96.f) + LOG2FD(b0[r]);
          if (a1[q][r] < T1F) r1[r] = (hm[q] - 96.f) + LOG2FD(b1[r]);
          mybad |= (a0[q][r] < T1F) && (b0[r] < T1F);
          mybad |= (a1[q][r] < T1F) && (b1[r] < T1F);
        }
        if (__any(mybad)) {         // beyond 192 log2-units: exact fixup (very rare)
          float4 h0 = {Hq[q][0], Hq[q][1], Hq[q][2], Hq[q][3]};
          float4 h1 = {Hq[q][4], Hq[q][5], Hq[q][6], Hq[q][7]};
          *(float4*)&Hdump[b15*36 + 8*g]     = h0;
          *(float4*)&Hdump[b15*36 + 8*g + 4] = h1;
          asm volatile("" ::: "memory");
          const float* HB = &Hdump[b15*36];
#pragma unroll
          for (int r = 0; r < 4; ++r) {
            if ((a0[q][r] < T1F) && (b0[r] < T1F)) r0[r] = exact_lse(pos2, HB, 4*g + r, inv);
            if ((a1[q][r] < T1F) && (b1[r] < T1F)) r1[r] = exact_lse(pos2, HB, 16 + 4*g + r, inv);
          }
        }
      }
    }
    float4 v0 = {nde*r0[0], nde*r0[1], nde*r0[2], nde*r0[3]};
    float4 v1 = {nde*r1[0], nde*r1[1], nde*r1[2], nde*r1[3]};
    float* Tq = Ts + q * 576;
    *(float4*)&Tq[b15*36 + 4*g]      = v0;   // D-layout: batch b15, rows 4g+r
    *(float4*)&Tq[b15*36 + 4*g + 16] = v1;   // rows 16+4g+r
  }
}

__global__ __launch_bounds__(64, 2) void sink_kernel(
    const float* __restrict__ pred, const float* __restrict__ tgt,
    const float* __restrict__ pos, float* __restrict__ ws) {
  __shared__ __align__(16) float sT[4][576];   // [slot][b*36+i] transpose buffer
  __shared__ __align__(16) float sHb[16][36];  // fallback H dump, [batch][j]

  const int lid = threadIdx.x;          // 0..63 (one wave per block)
  const int b15 = lid & 15;
  const int g   = lid >> 4;
  const int bbase = blockIdx.x * 16;    // this wave's 16 batches
  const float2* pos2 = (const float2*)pos;
  float* Tw = &sT[0][0];
  float* Hd = &sHb[0][0];

  float al2[8], bl2[8];
  {
    const float* pr = &pred[(bbase + b15) * 32 + 8 * g];
    const float* tr = &tgt [(bbase + b15) * 32 + 8 * g];
    float4 p0 = *(const float4*)&pr[0];
    float4 p1 = *(const float4*)&pr[4];
    float4 t0 = *(const float4*)&tr[0];
    float4 t1 = *(const float4*)&tr[4];
    al2[0]=LOG2FD(p0.x); al2[1]=LOG2FD(p0.y); al2[2]=LOG2FD(p0.z); al2[3]=LOG2FD(p0.w);
    al2[4]=LOG2FD(p1.x); al2[5]=LOG2FD(p1.y); al2[6]=LOG2FD(p1.z); al2[7]=LOG2FD(p1.w);
    bl2[0]=LOG2FD(t0.x); bl2[1]=LOG2FD(t0.y); bl2[2]=LOG2FD(t0.z); bl2[3]=LOG2FD(t0.w);
    bl2[4]=LOG2FD(t1.x); bl2[5]=LOG2FD(t1.y); bl2[6]=LOG2FD(t1.z); bl2[7]=LOG2FD(t1.w);
  }
  float c2a[8], c2b[8];   // C*log2e rows b15 and b15+16, cols j=8g+e (A-layout)
  {
    float2 pm0 = pos2[b15];
    float2 pm1 = pos2[b15 + 16];
#pragma unroll
    for (int e = 0; e < 8; ++e) {
      float2 pj = pos2[8*g + e];
      float dx0 = pm0.x - pj.x, dy0 = pm0.y - pj.y;
      float dx1 = pm1.x - pj.x, dy1 = pm1.y - pj.y;
      c2a[e] = (0.5f*L2E)*(dx0*dx0 + dy0*dy0);
      c2b[e] = (0.5f*L2E)*(dx1*dx1 + dy1*dy1);
    }
  }

  bf16x8 KA1, KA2, KB1, KB2;
  float Fba[8], Gab[8], Faa[8], Gbb[8];

  // ---- init at eps0 = 8: slot0 = softmin(bl2) -> F_ba, slot1 = softmin(al2) -> G_ab
  buildK(c2a, c2b, 0.125f, KA1, KA2, KB1, KB2);
  {
    float Hq[2][8];
#pragma unroll
    for (int e = 0; e < 8; ++e) { Hq[0][e] = bl2[e]; Hq[1][e] = al2[e]; }
    ksoft_multi<2, false>(Tw, Hd, Hq, KA1, KA2, KB1, KB2, -8.f/9.f, 0.125f, b15, g, pos2);
  }
  pot_assign(Fba, Tw + 0*576, b15, g);
  pot_assign(Gab, Tw + 1*576, b15, g);
#pragma unroll
  for (int e = 0; e < 8; ++e) { Faa[e] = Gab[e]; Gbb[e] = Fba[e]; }

  // eps schedule [8, 8, 2, 0.5, 0.125 | 0.03125, 0.01, 0.01-extrap]
  const float INV[8] = {0.125f, 0.125f, 0.5f, 2.f, 8.f, 32.f, 100.f, 100.f};
  const float NDE[8] = {-8.f/9.f, -8.f/9.f, -2.f/3.f, -1.f/3.f, -1.f/9.f,
                        -1.f/33.f, -1.f/101.f, -1.f/101.f};
  float curInv = 0.125f;

  // ---- phase A: k = 0..4 (unchecked) ----
#pragma unroll 1
  for (int k = 0; k < 5; ++k) {
    const float inv = INV[k], nde = NDE[k];
    if (inv != curInv) { buildK(c2a, c2b, inv, KA1, KA2, KB1, KB2); curInv = inv; }
    float Hq[4][8];
#pragma unroll
    for (int e = 0; e < 8; ++e) {
      Hq[0][e] = fmaf(Gab[e], inv, bl2[e]);   // ft -> slot0 (F_ba)
      Hq[1][e] = fmaf(Fba[e], inv, al2[e]);   // gt -> slot1 (G_ab)
      Hq[2][e] = fmaf(Faa[e], inv, al2[e]);   // fa -> slot2 (F_aa)
      Hq[3][e] = fmaf(Gbb[e], inv, bl2[e]);   // gb -> slot3 (G_bb)
    }
    ksoft_multi<4, false>(Tw, Hd, Hq, KA1, KA2, KB1, KB2, nde, inv, b15, g, pos2);
    pot_merge(Fba, Tw + 0*576, b15, g);
    pot_merge(Gab, Tw + 1*576, b15, g);
    pot_merge(Faa, Tw + 2*576, b15, g);
    pot_merge(Gbb, Tw + 3*576, b15, g);
  }

  // ---- phase B: k = 5..7 (checked; k=7 is the final extrapolation, assign) ----
#pragma unroll 1
  for (int k = 5; k < 8; ++k) {
    const float inv = INV[k], nde = NDE[k];
    if (inv != curInv) { buildK(c2a, c2b, inv, KA1, KA2, KB1, KB2); curInv = inv; }
    const bool avg = (k < 7);
    float Hq[4][8];
#pragma unroll
    for (int e = 0; e < 8; ++e) {
      Hq[0][e] = fmaf(Gab[e], inv, bl2[e]);
      Hq[1][e] = fmaf(Fba[e], inv, al2[e]);
      Hq[2][e] = fmaf(Faa[e], inv, al2[e]);
      Hq[3][e] = fmaf(Gbb[e], inv, bl2[e]);
    }
    ksoft_multi<4, true>(Tw, Hd, Hq, KA1, KA2, KB1, KB2, nde, inv, b15, g, pos2);
    if (avg) {
      pot_merge(Fba, Tw + 0*576, b15, g);
      pot_merge(Gab, Tw + 1*576, b15, g);
      pot_merge(Faa, Tw + 2*576, b15, g);
      pot_merge(Gbb, Tw + 3*576, b15, g);
    } else {
      pot_assign(Fba, Tw + 0*576, b15, g);
      pot_assign(Gab, Tw + 1*576, b15, g);
      pot_assign(Faa, Tw + 2*576, b15, g);
      pot_assign(Gbb, Tw + 3*576, b15, g);
    }
  }

  // ---- loss: per-lane partial over its 8 (batch b15, j) entries ----
  float c = 0.f;
#pragma unroll
  for (int e = 0; e < 8; ++e) {
    c += EXP2F(al2[e]) * (EXP2F(-Faa[e]) - EXP2F(-Fba[e]))
       + EXP2F(bl2[e]) * (EXP2F(-Gbb[e]) - EXP2F(-Gab[e]));
  }
  c += __shfl_xor(c, 1);
  c += __shfl_xor(c, 2);
  c += __shfl_xor(c, 4);
  c += __shfl_xor(c, 8);
  c += __shfl_xor(c, 16);
  c += __shfl_xor(c, 32);
  if (lid == 0) ws[blockIdx.x] = c;
}

__global__ __launch_bounds__(256) void reduce_kernel(
    const float* __restrict__ ws, float* __restrict__ out, int n, float scale) {
  float s = 0.f;
  for (int i = threadIdx.x; i < n; i += 256) s += ws[i];
  s += __shfl_xor(s, 32);
  s += __shfl_xor(s, 16);
  s += __shfl_xor(s, 8);
  s += __shfl_xor(s, 4);
  s += __shfl_xor(s, 2);
  s += __shfl_xor(s, 1);
  __shared__ float a[4];
  if ((threadIdx.x & 63) == 0) a[threadIdx.x >> 6] = s;
  __syncthreads();
  if (threadIdx.x == 0) out[0] = ((a[0] + a[1]) + (a[2] + a[3])) * scale;
}

extern "C" void kernel_launch(void* const* d_in, const int* in_sizes, int n_in,
                              void* d_out, int out_size, void* d_ws, size_t ws_size,
                              hipStream_t stream) {
  const float* pred = (const float*)d_in[0];
  const float* tgt  = (const float*)d_in[1];
  const float* pos  = (const float*)d_in[2];
  const int B = in_sizes[0] / 32;        // 32768 batches
  const int nblocks = B / 16;            // 16 batches per 64-thread wave = 2048
  float* ws = (float*)d_ws;

  sink_kernel<<<nblocks, 64, 0, stream>>>(pred, tgt, pos, ws);
  reduce_kernel<<<1, 256, 0, stream>>>(ws, (float*)d_out, nblocks,
                                       1.005f / (float)B);
}

// Round 15
// 25.839 us; speedup vs baseline: 1.5587x; 1.0426x over previous
//
#include <hip/hip_runtime.h>
#include <hip/hip_bf16.h>

#define EXP2F(x)  __builtin_amdgcn_exp2f(x)    // v_exp_f32 = 2^x
#define LOG2FD(x) __builtin_amdgcn_logf(x)     // v_log_f32 = log2(x)
#define L2E 1.4426950408889634f
#define T1F 1.2621774e-29f                     // 2^-96: min trustworthy MFMA sum

typedef __attribute__((ext_vector_type(8))) short bf16x8;  // 8 bf16 = 4 VGPR
typedef __attribute__((ext_vector_type(4))) float f32x4;
typedef __attribute__((ext_vector_type(2))) unsigned int u32x2;

#define MFMA16(A, B, C) __builtin_amdgcn_mfma_f32_16x16x32_bf16((A), (B), (C), 0, 0, 0)

union U8 { unsigned int u[4]; bf16x8 v; };
union U8S { unsigned short s[8]; bf16x8 v; };

// split 8 f32 into bf16-truncated hi + bf16-truncated residual lo (K build only;
// K is shared across ALL batches so its rounding error is systematic -> keep split)
__device__ __forceinline__ void split_pack(const float* w, bf16x8& hi, bf16x8& lo) {
  U8 a, b;
#pragma unroll
  for (int k = 0; k < 4; ++k) {
    float x0 = w[2*k], x1 = w[2*k+1];
    unsigned u0 = __float_as_uint(x0) & 0xFFFF0000u;
    unsigned u1 = __float_as_uint(x1) & 0xFFFF0000u;
    float r0 = x0 - __uint_as_float(u0);
    float r1 = x1 - __uint_as_float(u1);
    a.u[k] = (u0 >> 16) | u1;
    b.u[k] = ((__float_as_uint(r0) & 0xFFFF0000u) >> 16) |
             (__float_as_uint(r1) & 0xFFFF0000u);
  }
  hi = a.v; lo = b.v;
}

// single bf16 pack via compiler RNE casts (compiler emits v_cvt_pk_bf16_f32).
// w's rounding error is per-batch random -> cancels in the 32768-batch mean.
__device__ __forceinline__ bf16x8 pack_bf16(const float* w) {
  U8S a;
#pragma unroll
  for (int e = 0; e < 8; ++e) {
    __hip_bfloat16 b = __float2bfloat16(w[e]);
    a.s[e] = reinterpret_cast<const unsigned short&>(b);
  }
  return a.v;
}

// xor-32 max via permlane32_swap (VALU pipe, no LDS)
__device__ __forceinline__ float pmax32(float v) {
  u32x2 r = __builtin_amdgcn_permlane32_swap(__float_as_uint(v), __float_as_uint(v),
                                             false, false);
  return fmaxf(__uint_as_float(r.x), __uint_as_float(r.y));
}

__device__ __forceinline__ void buildK(const float* c2a, const float* c2b, float inv,
                                       bf16x8& KA1, bf16x8& KA2, bf16x8& KB1, bf16x8& KB2) {
  float ka[8], kb[8];
#pragma unroll
  for (int e = 0; e < 8; ++e) { ka[e] = EXP2F(-c2a[e] * inv); kb[e] = EXP2F(-c2b[e] * inv); }
  split_pack(ka, KA1, KA2);
  split_pack(kb, KB1, KB2);
}

__device__ __forceinline__ void pot_assign(float* pot, const float* Ts, int b15, int g) {
  float4 r0 = *(const float4*)&Ts[b15*36 + 8*g];
  float4 r1 = *(const float4*)&Ts[b15*36 + 8*g + 4];
  pot[0]=r0.x; pot[1]=r0.y; pot[2]=r0.z; pot[3]=r0.w;
  pot[4]=r1.x; pot[5]=r1.y; pot[6]=r1.z; pot[7]=r1.w;
}

__device__ __forceinline__ void pot_merge(float* pot, const float* Ts, int b15, int g) {
  float4 r0 = *(const float4*)&Ts[b15*36 + 8*g];
  float4 r1 = *(const float4*)&Ts[b15*36 + 8*g + 4];
  pot[0]=0.5f*(pot[0]+r0.x); pot[1]=0.5f*(pot[1]+r0.y);
  pot[2]=0.5f*(pot[2]+r0.z); pot[3]=0.5f*(pot[3]+r0.w);
  pot[4]=0.5f*(pot[4]+r1.x); pot[5]=0.5f*(pot[5]+r1.y);
  pot[6]=0.5f*(pot[6]+r1.z); pot[7]=0.5f*(pot[7]+r1.w);
}

// rare exact per-row logsumexp: arg_j = H_j - c2(i,j)*inv, H from LDS row
__device__ __noinline__ float exact_lse(const float2* pos2, const float* HB,
                                        int i, float inv) {
  float2 pi = pos2[i];
  float m = -3.4e38f;
#pragma unroll 1
  for (int j = 0; j < 32; ++j) {
    float2 pj = pos2[j];
    float dx = pi.x - pj.x, dy = pi.y - pj.y;
    float arg = fmaf((0.5f*L2E)*(dx*dx + dy*dy), -inv, HB[j]);
    m = fmaxf(m, arg);
  }
  float s = 0.f;
#pragma unroll 1
  for (int j = 0; j < 32; ++j) {
    float2 pj = pos2[j];
    float dx = pi.x - pj.x, dy = pi.y - pj.y;
    float arg = fmaf((0.5f*L2E)*(dx*dx + dy*dy), -inv, HB[j]);
    s += EXP2F(arg - m);
  }
  return m + LOG2FD(s);
}

// NQ interleaved MFMA softmins for 16 batches each (stage-by-stage ILP).
// Hq[q] in B-layout; result nde*raw stored D-layout to slot q of Ts.
// w is single bf16 (RNE); K keeps hi/lo split -> 4 MFMAs per softmin.
template<int NQ, bool CHECKED>
__device__ __forceinline__ void ksoft_multi(float* Ts, float* Hdump,
    const float Hq[][8], bf16x8 KA1, bf16x8 KA2, bf16x8 KB1, bf16x8 KB2,
    float nde, float inv, int b15, int g, const float2* pos2) {
  float hm[NQ], d[NQ][8];
  bf16x8 w1[NQ];
  // stage 1: batch-max + exp + pack (independent per q)
#pragma unroll
  for (int q = 0; q < NQ; ++q) {
    const float* H = Hq[q];
    float m = fmaxf(fmaxf(fmaxf(H[0], H[1]), fmaxf(H[2], H[3])),
                    fmaxf(fmaxf(H[4], H[5]), fmaxf(H[6], H[7])));
    m = fmaxf(m, __shfl_xor(m, 16));
    m = pmax32(m);
    hm[q] = m;
    float w[8];
#pragma unroll
    for (int e = 0; e < 8; ++e) { d[q][e] = H[e] - m; w[e] = EXP2F(d[q][e]); }
    w1[q] = pack_bf16(w);
  }
  // stage 2: 4*NQ MFMAs in 2 rounds of 2*NQ independent ops
  f32x4 a0[NQ], a1[NQ];
  const f32x4 z = {0.f, 0.f, 0.f, 0.f};
#pragma unroll
  for (int q = 0; q < NQ; ++q) { a0[q] = MFMA16(KA1, w1[q], z);     a1[q] = MFMA16(KB1, w1[q], z); }
#pragma unroll
  for (int q = 0; q < NQ; ++q) { a0[q] = MFMA16(KA2, w1[q], a0[q]); a1[q] = MFMA16(KB2, w1[q], a1[q]); }
  // stage 3: logs (+rare rescue), store
#pragma unroll
  for (int q = 0; q < NQ; ++q) {
    float r0[4], r1[4];
#pragma unroll
    for (int r = 0; r < 4; ++r) {
      r0[r] = hm[q] + LOG2FD(a0[q][r]);
      r1[r] = hm[q] + LOG2FD(a1[q][r]);
    }
    if (CHECKED) {
      float mn = fminf(fminf(fminf(a0[q][0], a0[q][1]), fminf(a0[q][2], a0[q][3])),
                       fminf(fminf(a1[q][0], a1[q][1]), fminf(a1[q][2], a1[q][3])));
      if (__any(mn < T1F)) {        // rescue scale (+96)
        float wb[8];
#pragma unroll
        for (int e = 0; e < 8; ++e) wb[e] = EXP2F(d[q][e] + 96.f);
        bf16x8 u1 = pack_bf16(wb);
        f32x4 b0 = MFMA16(KA1, u1, z);
        b0 = MFMA16(KA2, u1, b0);
        f32x4 b1 = MFMA16(KB1, u1, z);
        b1 = MFMA16(KB2, u1, b1);
        bool mybad = false;
#pragma unroll
        for (int r = 0; r < 4; ++r) {
          if (a0[q][r] < T1F) r0[r] = (hm[q] - 96.f) + LOG2FD(b0[r]);
          if (a1[q][r] < T1F) r1[r] = (hm[q] - 96.f) + LOG2FD(b1[r]);
          mybad |= (a0[q][r] < T1F) && (b0[r] < T1F);
          mybad |= (a1[q][r] < T1F) && (b1[r] < T1F);
        }
        if (__any(mybad)) {         // beyond 192 log2-units: exact fixup (very rare)
          float4 h0 = {Hq[q][0], Hq[q][1], Hq[q][2], Hq[q][3]};
          float4 h1 = {Hq[q][4], Hq[q][5], Hq[q][6], Hq[q][7]};
          *(float4*)&Hdump[b15*36 + 8*g]     = h0;
          *(float4*)&Hdump[b15*36 + 8*g + 4] = h1;
          asm volatile("" ::: "memory");
          const float* HB = &Hdump[b15*36];
#pragma unroll
          for (int r = 0; r < 4; ++r) {
            if ((a0[q][r] < T1F) && (b0[r] < T1F)) r0[r] = exact_lse(pos2, HB, 4*g + r, inv);
            if ((a1[q][r] < T1F) && (b1[r] < T1F)) r1[r] = exact_lse(pos2, HB, 16 + 4*g + r, inv);
          }
        }
      }
    }
    float4 v0 = {nde*r0[0], nde*r0[1], nde*r0[2], nde*r0[3]};
    float4 v1 = {nde*r1[0], nde*r1[1], nde*r1[2], nde*r1[3]};
    float* Tq = Ts + q * 576;
    *(float4*)&Tq[b15*36 + 4*g]      = v0;   // D-layout: batch b15, rows 4g+r
    *(float4*)&Tq[b15*36 + 4*g + 16] = v1;   // rows 16+4g+r
  }
}

__global__ __launch_bounds__(64, 2) void sink_kernel(
    const float* __restrict__ pred, const float* __restrict__ tgt,
    const float* __restrict__ pos, float* __restrict__ ws) {
  __shared__ __align__(16) float sT[4][576];   // [slot][b*36+i] transpose buffer
  __shared__ __align__(16) float sHb[16][36];  // fallback H dump, [batch][j]

  const int lid = threadIdx.x;          // 0..63 (one wave per block)
  const int b15 = lid & 15;
  const int g   = lid >> 4;
  const int bbase = blockIdx.x * 16;    // this wave's 16 batches
  const float2* pos2 = (const float2*)pos;
  float* Tw = &sT[0][0];
  float* Hd = &sHb[0][0];

  float al2[8], bl2[8];
  {
    const float* pr = &pred[(bbase + b15) * 32 + 8 * g];
    const float* tr = &tgt [(bbase + b15) * 32 + 8 * g];
    float4 p0 = *(const float4*)&pr[0];
    float4 p1 = *(const float4*)&pr[4];
    float4 t0 = *(const float4*)&tr[0];
    float4 t1 = *(const float4*)&tr[4];
    al2[0]=LOG2FD(p0.x); al2[1]=LOG2FD(p0.y); al2[2]=LOG2FD(p0.z); al2[3]=LOG2FD(p0.w);
    al2[4]=LOG2FD(p1.x); al2[5]=LOG2FD(p1.y); al2[6]=LOG2FD(p1.z); al2[7]=LOG2FD(p1.w);
    bl2[0]=LOG2FD(t0.x); bl2[1]=LOG2FD(t0.y); bl2[2]=LOG2FD(t0.z); bl2[3]=LOG2FD(t0.w);
    bl2[4]=LOG2FD(t1.x); bl2[5]=LOG2FD(t1.y); bl2[6]=LOG2FD(t1.z); bl2[7]=LOG2FD(t1.w);
  }
  float c2a[8], c2b[8];   // C*log2e rows b15 and b15+16, cols j=8g+e (A-layout)
  {
    float2 pm0 = pos2[b15];
    float2 pm1 = pos2[b15 + 16];
#pragma unroll
    for (int e = 0; e < 8; ++e) {
      float2 pj = pos2[8*g + e];
      float dx0 = pm0.x - pj.x, dy0 = pm0.y - pj.y;
      float dx1 = pm1.x - pj.x, dy1 = pm1.y - pj.y;
      c2a[e] = (0.5f*L2E)*(dx0*dx0 + dy0*dy0);
      c2b[e] = (0.5f*L2E)*(dx1*dx1 + dy1*dy1);
    }
  }

  bf16x8 KA1, KA2, KB1, KB2;
  float Fba[8], Gab[8], Faa[8], Gbb[8];

  // ---- init at eps0 = 8: slot0 = softmin(bl2) -> F_ba, slot1 = softmin(al2) -> G_ab
  buildK(c2a, c2b, 0.125f, KA1, KA2, KB1, KB2);
  {
    float Hq[2][8];
#pragma unroll
    for (int e = 0; e < 8; ++e) { Hq[0][e] = bl2[e]; Hq[1][e] = al2[e]; }
    ksoft_multi<2, false>(Tw, Hd, Hq, KA1, KA2, KB1, KB2, -8.f/9.f, 0.125f, b15, g, pos2);
  }
  pot_assign(Fba, Tw + 0*576, b15, g);
  pot_assign(Gab, Tw + 1*576, b15, g);
#pragma unroll
  for (int e = 0; e < 8; ++e) { Faa[e] = Gab[e]; Gbb[e] = Fba[e]; }

  // eps schedule [8, 8, 2, 0.5, 0.125 | 0.03125, 0.01, 0.01-extrap]
  // Fully unrolled: constants fold, and each iteration's buildK for the NEXT
  // eps is issued between ksoft and pot_merge (independent of the potentials)
  // so its exps overlap the MFMA->log->LDS shadow of the current iteration.
  const float INV[8] = {0.125f, 0.125f, 0.5f, 2.f, 8.f, 32.f, 100.f, 100.f};
  const float NDE[8] = {-8.f/9.f, -8.f/9.f, -2.f/3.f, -1.f/3.f, -1.f/9.f,
                        -1.f/33.f, -1.f/101.f, -1.f/101.f};

  // ---- phase A: k = 0..4 (unchecked) ----
#pragma unroll
  for (int k = 0; k < 5; ++k) {
    const float inv = INV[k], nde = NDE[k];
    float Hq[4][8];
#pragma unroll
    for (int e = 0; e < 8; ++e) {
      Hq[0][e] = fmaf(Gab[e], inv, bl2[e]);   // ft -> slot0 (F_ba)
      Hq[1][e] = fmaf(Fba[e], inv, al2[e]);   // gt -> slot1 (G_ab)
      Hq[2][e] = fmaf(Faa[e], inv, al2[e]);   // fa -> slot2 (F_aa)
      Hq[3][e] = fmaf(Gbb[e], inv, bl2[e]);   // gb -> slot3 (G_bb)
    }
    ksoft_multi<4, false>(Tw, Hd, Hq, KA1, KA2, KB1, KB2, nde, inv, b15, g, pos2);
    if (INV[k+1] != inv)            // folds at compile time (k is unrolled)
      buildK(c2a, c2b, INV[k+1], KA1, KA2, KB1, KB2);
    pot_merge(Fba, Tw + 0*576, b15, g);
    pot_merge(Gab, Tw + 1*576, b15, g);
    pot_merge(Faa, Tw + 2*576, b15, g);
    pot_merge(Gbb, Tw + 3*576, b15, g);
  }

  // ---- phase B: k = 5..7 (checked; k=7 is the final extrapolation, assign) ----
#pragma unroll
  for (int k = 5; k < 8; ++k) {
    const float inv = INV[k], nde = NDE[k];
    const bool avg = (k < 7);
    float Hq[4][8];
#pragma unroll
    for (int e = 0; e < 8; ++e) {
      Hq[0][e] = fmaf(Gab[e], inv, bl2[e]);
      Hq[1][e] = fmaf(Fba[e], inv, al2[e]);
      Hq[2][e] = fmaf(Faa[e], inv, al2[e]);
      Hq[3][e] = fmaf(Gbb[e], inv, bl2[e]);
    }
    ksoft_multi<4, true>(Tw, Hd, Hq, KA1, KA2, KB1, KB2, nde, inv, b15, g, pos2);
    if (k < 7 && INV[k+1] != inv)   // folds: only k=5 builds (inv 32 -> 100)
      buildK(c2a, c2b, INV[k+1], KA1, KA2, KB1, KB2);
    if (avg) {
      pot_merge(Fba, Tw + 0*576, b15, g);
      pot_merge(Gab, Tw + 1*576, b15, g);
      pot_merge(Faa, Tw + 2*576, b15, g);
      pot_merge(Gbb, Tw + 3*576, b15, g);
    } else {
      pot_assign(Fba, Tw + 0*576, b15, g);
      pot_assign(Gab, Tw + 1*576, b15, g);
      pot_assign(Faa, Tw + 2*576, b15, g);
      pot_assign(Gbb, Tw + 3*576, b15, g);
    }
  }

  // ---- loss: per-lane partial over its 8 (batch b15, j) entries ----
  float c = 0.f;
#pragma unroll
  for (int e = 0; e < 8; ++e) {
    c += EXP2F(al2[e]) * (EXP2F(-Faa[e]) - EXP2F(-Fba[e]))
       + EXP2F(bl2[e]) * (EXP2F(-Gbb[e]) - EXP2F(-Gab[e]));
  }
  c += __shfl_xor(c, 1);
  c += __shfl_xor(c, 2);
  c += __shfl_xor(c, 4);
  c += __shfl_xor(c, 8);
  c += __shfl_xor(c, 16);
  c += __shfl_xor(c, 32);
  if (lid == 0) ws[blockIdx.x] = c;
}

__global__ __launch_bounds__(256) void reduce_kernel(
    const float* __restrict__ ws, float* __restrict__ out, int n, float scale) {
  float s = 0.f;
  for (int i = threadIdx.x; i < n; i += 256) s += ws[i];
  s += __shfl_xor(s, 32);
  s += __shfl_xor(s, 16);
  s += __shfl_xor(s, 8);
  s += __shfl_xor(s, 4);
  s += __shfl_xor(s, 2);
  s += __shfl_xor(s, 1);
  __shared__ float a[4];
  if ((threadIdx.x & 63) == 0) a[threadIdx.x >> 6] = s;
  __syncthreads();
  if (threadIdx.x == 0) out[0] = ((a[0] + a[1]) + (a[2] + a[3])) * scale;
}

extern "C" void kernel_launch(void* const* d_in, const int* in_sizes, int n_in,
                              void* d_out, int out_size, void* d_ws, size_t ws_size,
                              hipStream_t stream) {
  const float* pred = (const float*)d_in[0];
  const float* tgt  = (const float*)d_in[1];
  const float* pos  = (const float*)d_in[2];
  const int B = in_sizes[0] / 32;        // 32768 batches
  const int nblocks = B / 16;            // 16 batches per 64-thread wave = 2048
  float* ws = (float*)d_ws;

  sink_kernel<<<nblocks, 64, 0, stream>>>(pred, tgt, pos, ws);
  reduce_kernel<<<1, 256, 0, stream>>>(ws, (float*)d_out, nblocks,
                                       1.005f / (float)B);
}